// Round 1
// baseline (140.883 us; speedup 1.0000x reference)
//
#include <hip/hip_runtime.h>

// PositionAwareARCEncoder fused kernels.
// B=32768, H=W=5, NC=4, E=64, HID=128, OUT=128, NH=4, HD=16.
//
// Table factorization:
//  inpval[c][ij][64]  = input-MLP(concat(color_embed[c], pos[ij]))
//  ktab[c][ij][64]    = inpval @ k_w + k_b
//  vtab[c][ij][64]    = inpval @ v_w + v_b
//  outval[c][ij][64]  = output-MLP(concat(color_embed[c], pos[ij]))
//  outproj[c][ij][128]= (outval @ cb_w1[64:128]) / 25
//  qtab[p][64]        = cpe(p) @ q_w + q_b          (p=25 -> cpe=0 -> q_b)
//  cpeproj[p][128]    = cpe(p) @ cb_w1[128:192]     (p=25 -> 0)
//  wov[64][128]       = o_w @ cb_w1[0:64]
//  bias1[128]         = cb_b1 + o_b @ cb_w1[0:64]

__global__ void prep12(const float* __restrict__ color_embed,
                       const float* __restrict__ row_embed,
                       const float* __restrict__ col_embed,
                       const float* __restrict__ ip_w1, const float* __restrict__ ip_b1,
                       const float* __restrict__ ip_w2, const float* __restrict__ ip_b2,
                       const float* __restrict__ op_w1, const float* __restrict__ op_b1,
                       const float* __restrict__ op_w2, const float* __restrict__ op_b2,
                       float* __restrict__ inpval, float* __restrict__ outval) {
  __shared__ float feat[128];
  __shared__ float h1[128];
  const int bid = blockIdx.x;       // 0..199
  const int path = bid / 100;       // 0: input MLP, 1: output MLP
  const int cij = bid % 100;
  const int c = cij / 25, ij = cij % 25, gi = ij / 5, gj = ij % 5;
  const int t = threadIdx.x;        // 128 threads
  if (t < 64)      feat[t] = color_embed[c * 64 + t];
  else if (t < 96) feat[t] = row_embed[gi * 32 + (t - 64)];
  else             feat[t] = col_embed[gj * 32 + (t - 96)];
  __syncthreads();
  const float* w1 = path ? op_w1 : ip_w1;
  const float* b1 = path ? op_b1 : ip_b1;
  float acc = b1[t];
#pragma unroll 8
  for (int d = 0; d < 128; ++d) acc = fmaf(feat[d], w1[d * 128 + t], acc);
  h1[t] = fmaxf(acc, 0.f);
  __syncthreads();
  if (t < 64) {
    const float* w2 = path ? op_w2 : ip_w2;
    const float* b2 = path ? op_b2 : ip_b2;
    float v = b2[t];
#pragma unroll 8
    for (int d = 0; d < 128; ++d) v = fmaf(h1[d], w2[d * 64 + t], v);
    (path ? outval : inpval)[cij * 64 + t] = v;
  }
}

__global__ void prep3(const float* __restrict__ row_embed, const float* __restrict__ col_embed,
                      const float* __restrict__ k_w, const float* __restrict__ k_b,
                      const float* __restrict__ v_w, const float* __restrict__ v_b,
                      const float* __restrict__ q_w, const float* __restrict__ q_b,
                      const float* __restrict__ o_w, const float* __restrict__ o_b,
                      const float* __restrict__ cb_w1, const float* __restrict__ cb_b1,
                      const float* __restrict__ inpval, const float* __restrict__ outval,
                      float* __restrict__ ktab, float* __restrict__ vtab,
                      float* __restrict__ outproj, float* __restrict__ qtab,
                      float* __restrict__ cpeproj, float* __restrict__ wov,
                      float* __restrict__ bias1) {
  const int tid = blockIdx.x * 256 + threadIdx.x;
  if (tid < 6400) {                       // ktab[100][64]
    const int cij = tid >> 6, e2 = tid & 63;
    const float* x = inpval + cij * 64;
    float a = k_b[e2];
#pragma unroll 8
    for (int e = 0; e < 64; ++e) a = fmaf(x[e], k_w[e * 64 + e2], a);
    ktab[tid] = a;
  } else if (tid < 12800) {               // vtab[100][64]
    const int l = tid - 6400;
    const int cij = l >> 6, e2 = l & 63;
    const float* x = inpval + cij * 64;
    float a = v_b[e2];
#pragma unroll 8
    for (int e = 0; e < 64; ++e) a = fmaf(x[e], v_w[e * 64 + e2], a);
    vtab[l] = a;
  } else if (tid < 25600) {               // outproj[100][128] (1/25 folded)
    const int l = tid - 12800;
    const int cij = l >> 7, jj = l & 127;
    const float* x = outval + cij * 64;
    float a = 0.f;
#pragma unroll 8
    for (int e = 0; e < 64; ++e) a = fmaf(x[e], cb_w1[(64 + e) * 128 + jj], a);
    outproj[l] = a * (1.f / 25.f);
  } else if (tid < 27264) {               // qtab[26][64]
    const int l = tid - 25600;
    const int p = l >> 6, e2 = l & 63;
    float a = q_b[e2];
    if (p < 25) {
      const int r = p / 5, c = p % 5;
#pragma unroll 8
      for (int e = 0; e < 32; ++e) a = fmaf(row_embed[r * 32 + e], q_w[e * 64 + e2], a);
#pragma unroll 8
      for (int e = 0; e < 32; ++e) a = fmaf(col_embed[c * 32 + e], q_w[(32 + e) * 64 + e2], a);
    }
    qtab[l] = a;
  } else if (tid < 30592) {               // cpeproj[26][128]
    const int l = tid - 27264;
    const int p = l >> 7, jj = l & 127;
    float a = 0.f;
    if (p < 25) {
      const int r = p / 5, c = p % 5;
#pragma unroll 8
      for (int e = 0; e < 32; ++e) a = fmaf(row_embed[r * 32 + e], cb_w1[(128 + e) * 128 + jj], a);
#pragma unroll 8
      for (int e = 0; e < 32; ++e) a = fmaf(col_embed[c * 32 + e], cb_w1[(160 + e) * 128 + jj], a);
    }
    cpeproj[l] = a;
  } else if (tid < 38784) {               // wov[64][128]
    const int l = tid - 30592;
    const int d = l >> 7, jj = l & 127;
    float a = 0.f;
#pragma unroll 8
    for (int e = 0; e < 64; ++e) a = fmaf(o_w[d * 64 + e], cb_w1[e * 128 + jj], a);
    wov[l] = a;
  } else if (tid < 38912) {               // bias1[128]
    const int jj = tid - 38784;
    float a = cb_b1[jj];
#pragma unroll 8
    for (int e = 0; e < 64; ++e) a = fmaf(o_b[e], cb_w1[e * 128 + jj], a);
    bias1[jj] = a;
  }
}

// One wave (64 lanes) per batch element; lane = feature dim.
__global__ __launch_bounds__(256) void arc_main(
    const int* __restrict__ obs,
    const float* __restrict__ ktab, const float* __restrict__ vtab,
    const float* __restrict__ outproj, const float* __restrict__ qtab,
    const float* __restrict__ cpeproj, const float* __restrict__ wov,
    const float* __restrict__ bias1,
    const float* __restrict__ cb_w2, const float* __restrict__ cb_b2,
    float* __restrict__ out) {
  const int lane = threadIdx.x & 63;
  const int wv = threadIdx.x >> 6;
  const int b = blockIdx.x * 4 + wv;
  const int* ob = obs + b * 75;   // [0:25)=input_grid, [25:50)=output_grid, [50:75)=mask

  // Decode obs via ballots: 2 loads + 6 ballots instead of 75 broadcast loads.
  const int x = ob[lane];
  const int y = (lane < 11) ? ob[64 + lane] : 0;
  const unsigned long long ig_lo = __ballot((lane < 25) && (x & 1));
  const unsigned long long ig_hi = __ballot((lane < 25) && (x & 2));
  const unsigned long long og_lo = __ballot((lane >= 25) && (lane < 50) && (x & 1)) >> 25;
  const unsigned long long og_hi = __ballot((lane >= 25) && (lane < 50) && (x & 2)) >> 25;
  const unsigned long long mb =
      (__ballot((lane >= 50) && (x != 0)) >> 50) |
      (__ballot((lane < 11) && (y != 0)) << 14);
  const int cpe_idx = mb ? __builtin_ctzll((long long)mb) : 25;

  // q for this lane's (head, dim)
  const float q_l = qtab[cpe_idx * 64 + lane];

  // scores: lane group of 16 = one head; reduce over HD=16 via shfl_xor
  float sc[25];
#pragma unroll
  for (int ij = 0; ij < 25; ++ij) {
    const int ig = (int)((ig_lo >> ij) & 1ull) | ((int)((ig_hi >> ij) & 1ull) << 1);
    float p = q_l * ktab[(ig * 25 + ij) * 64 + lane];
    p += __shfl_xor(p, 1);
    p += __shfl_xor(p, 2);
    p += __shfl_xor(p, 4);
    p += __shfl_xor(p, 8);
    sc[ij] = p * 0.25f;   // HD^-0.5
  }
  // softmax over 25 (per head, redundant across the 16 lanes of the head)
  float mx = sc[0];
#pragma unroll
  for (int ij = 1; ij < 25; ++ij) mx = fmaxf(mx, sc[ij]);
  float s = 0.f;
#pragma unroll
  for (int ij = 0; ij < 25; ++ij) { sc[ij] = __expf(sc[ij] - mx); s += sc[ij]; }
  const float inv = 1.0f / s;

  // attended (pre o_w), lane-parallel
  float ra = 0.f;
#pragma unroll
  for (int ij = 0; ij < 25; ++ij) {
    const int ig = (int)((ig_lo >> ij) & 1ull) | ((int)((ig_hi >> ij) & 1ull) << 1);
    ra = fmaf(sc[ij], vtab[(ig * 25 + ij) * 64 + lane], ra);
  }
  ra *= inv;

  // hidden = relu(ra @ wov + outproj-sum + cpeproj + bias1); lane holds j=lane, lane+64
  float a0 = bias1[lane] + cpeproj[cpe_idx * 128 + lane];
  float a1 = bias1[64 + lane] + cpeproj[cpe_idx * 128 + 64 + lane];
#pragma unroll
  for (int ij = 0; ij < 25; ++ij) {
    const int og = (int)((og_lo >> ij) & 1ull) | ((int)((og_hi >> ij) & 1ull) << 1);
    const float* p = outproj + (og * 25 + ij) * 128;
    a0 += p[lane];
    a1 += p[64 + lane];
  }
#pragma unroll 8
  for (int d = 0; d < 64; ++d) {
    const float rd = __shfl(ra, d);
    a0 = fmaf(rd, wov[d * 128 + lane], a0);
    a1 = fmaf(rd, wov[d * 128 + 64 + lane], a1);
  }
  a0 = fmaxf(a0, 0.f);
  a1 = fmaxf(a1, 0.f);

  // out = hidden @ cb_w2 + cb_b2
  float o0 = cb_b2[lane], o1 = cb_b2[64 + lane];
#pragma unroll 8
  for (int j = 0; j < 64; ++j) {
    const float hj = __shfl(a0, j);
    o0 = fmaf(hj, cb_w2[j * 128 + lane], o0);
    o1 = fmaf(hj, cb_w2[j * 128 + 64 + lane], o1);
  }
#pragma unroll 8
  for (int j = 0; j < 64; ++j) {
    const float hj = __shfl(a1, j);
    o0 = fmaf(hj, cb_w2[(64 + j) * 128 + lane], o0);
    o1 = fmaf(hj, cb_w2[(64 + j) * 128 + 64 + lane], o1);
  }
  out[b * 128 + lane] = o0;
  out[b * 128 + 64 + lane] = o1;
}

extern "C" void kernel_launch(void* const* d_in, const int* in_sizes, int n_in,
                              void* d_out, int out_size, void* d_ws, size_t ws_size,
                              hipStream_t stream) {
  const int*   obs         = (const int*)d_in[0];
  const float* color_embed = (const float*)d_in[1];
  const float* row_embed   = (const float*)d_in[2];
  const float* col_embed   = (const float*)d_in[3];
  const float* ip_w1 = (const float*)d_in[4];
  const float* ip_b1 = (const float*)d_in[5];
  const float* ip_w2 = (const float*)d_in[6];
  const float* ip_b2 = (const float*)d_in[7];
  const float* q_w = (const float*)d_in[8];
  const float* q_b = (const float*)d_in[9];
  const float* k_w = (const float*)d_in[10];
  const float* k_b = (const float*)d_in[11];
  const float* v_w = (const float*)d_in[12];
  const float* v_b = (const float*)d_in[13];
  const float* o_w = (const float*)d_in[14];
  const float* o_b = (const float*)d_in[15];
  const float* op_w1 = (const float*)d_in[16];
  const float* op_b1 = (const float*)d_in[17];
  const float* op_w2 = (const float*)d_in[18];
  const float* op_b2 = (const float*)d_in[19];
  const float* cb_w1 = (const float*)d_in[20];
  const float* cb_b1 = (const float*)d_in[21];
  const float* cb_w2 = (const float*)d_in[22];
  const float* cb_b2 = (const float*)d_in[23];

  float* ws = (float*)d_ws;
  float* qtab    = ws;               // 26*64   = 1664
  float* cpeproj = qtab + 1664;      // 26*128  = 3328
  float* ktab    = cpeproj + 3328;   // 100*64  = 6400
  float* vtab    = ktab + 6400;      // 100*64  = 6400
  float* outproj = vtab + 6400;      // 100*128 = 12800
  float* wov     = outproj + 12800;  // 64*128  = 8192
  float* bias1   = wov + 8192;       // 128
  float* inpval  = bias1 + 128;      // 100*64  = 6400
  float* outval  = inpval + 6400;    // 100*64  = 6400
  // total 51712 floats = ~207 KB of d_ws

  prep12<<<200, 128, 0, stream>>>(color_embed, row_embed, col_embed,
                                  ip_w1, ip_b1, ip_w2, ip_b2,
                                  op_w1, op_b1, op_w2, op_b2, inpval, outval);
  prep3<<<152, 256, 0, stream>>>(row_embed, col_embed, k_w, k_b, v_w, v_b,
                                 q_w, q_b, o_w, o_b, cb_w1, cb_b1,
                                 inpval, outval,
                                 ktab, vtab, outproj, qtab, cpeproj, wov, bias1);
  arc_main<<<8192, 256, 0, stream>>>(obs, ktab, vtab, outproj, qtab, cpeproj,
                                     wov, bias1, cb_w2, cb_b2, (float*)d_out);
}